// Round 14
// baseline (296.954 us; speedup 1.0000x reference)
//
#include <hip/hip_runtime.h>
#include <hip/hip_bf16.h>

#define NSEG 512
#define NSPLIT 32
#define ZSTR 276   // ztile stride in shorts: 138 dwords = 10 mod 32 -> conflict-free (proven r9: 5.74M->225K)

typedef __attribute__((ext_vector_type(8))) short short8;
typedef __attribute__((ext_vector_type(4))) float floatx4;
typedef __attribute__((ext_vector_type(4))) unsigned uintx4;
typedef __attribute__((ext_vector_type(2))) unsigned uintx2;

// ws layout (bytes), all 16B-aligned
#define WS_WAT   0        // short [256][32]   WA^T
#define WS_WBT2  16384    // short [256][64]   WB^T (K padded 48->64 w/ zeros)
#define WS_W2GA  49152    // short [256][256]  (gA*Wback)^T
#define WS_W2GB  180224   // short [256][256]  (gB*Wback)^T
#define WS_C1A   311296   // float[256] gA . Wback[:,n]
#define WS_C2A   312320   // float[256] betaA . Wback[:,n] + bback
#define WS_C1B   313344
#define WS_C2B   314368
#define WS_INVA  315392   // float[32]  1/stdA
#define WS_INVB  315520   // float[48]  1/stdB
#define WS_VPART 315712   // float [NSPLIT][NSEG]
#define WS_CPART 381248   // float [NSPLIT][NSEG]
#define WS_NMIA  446848   // float[32]  -meanA/stdA
#define WS_NMIB  446976   // float[48]  -meanB/stdB
// end 447168

__device__ __forceinline__ short f2bf(float f) {  // RNE (prep tables only)
  unsigned u = __builtin_bit_cast(unsigned, f);
  u += 0x7FFFu + ((u >> 16) & 1u);
  return (short)(u >> 16);
}

// paired RNE f32->bf16; __float22bfloat162_rn lowers to v_cvt_pk_bf16_f32.
// (__hip_bfloat162 is not trivially copyable -> memcpy, not bit_cast; r11 fix)
__device__ __forceinline__ unsigned cvt2(float lo, float hi) {
  __hip_bfloat162 b = __float22bfloat162_rn(float2{lo, hi});
  unsigned r;
  __builtin_memcpy(&r, &b, 4);
  return r;
}

// ---- prep: weight tables + c1/c2 + inv/nmi + partial-buffer zeroing.
__global__ __launch_bounds__(256) void prep_kernel(
    const float* __restrict__ WA, const float* __restrict__ WB,
    const float* __restrict__ Wback,
    const float* __restrict__ gA, const float* __restrict__ betaA,
    const float* __restrict__ gB, const float* __restrict__ betaB,
    const float* __restrict__ bback,
    const float* __restrict__ sA, const float* __restrict__ sB,
    const float* __restrict__ mA, const float* __restrict__ mB,
    char* __restrict__ ws) {
  short* waT  = (short*)(ws + WS_WAT);
  short* wbT2 = (short*)(ws + WS_WBT2);
  short* w2gA = (short*)(ws + WS_W2GA);
  short* w2gB = (short*)(ws + WS_W2GB);
  float* invA = (float*)(ws + WS_INVA);
  float* invB = (float*)(ws + WS_INVB);
  float* nmiA = (float*)(ws + WS_NMIA);
  float* nmiB = (float*)(ws + WS_NMIB);
  float* vz   = (float*)(ws + WS_VPART);
  int tid = blockIdx.x * blockDim.x + threadIdx.x;
  int stride = gridDim.x * blockDim.x;
  if (tid < 32) { float iv = 1.0f / sA[tid]; invA[tid] = iv; nmiA[tid] = -mA[tid] * iv; }
  if (tid < 48) { float iv = 1.0f / sB[tid]; invB[tid] = iv; nmiB[tid] = -mB[tid] * iv; }
  // output-indexed (coalesced writes); strided reads are L2-absorbed
  for (int i = tid; i < 32*256; i += stride) {          // waT[n][k] = WA[k][n]
    int n = i >> 5, k = i & 31;
    waT[i] = f2bf(WA[k*256 + n]);
  }
  for (int i = tid; i < 256*64; i += stride) {          // wbT2[n][k] = WB[k][n], pad K
    int n = i >> 6, k = i & 63;
    wbT2[i] = (k < 48) ? f2bf(WB[k*256 + n]) : (short)0;
  }
  for (int i = tid; i < 256*256; i += stride) {         // w2g[n][k] = g[k]*Wback[k][n]
    int n = i >> 8, k = i & 255;
    float w = Wback[k*256 + n];
    w2gA[i] = f2bf(gA[k] * w);
    w2gB[i] = f2bf(gB[k] * w);
  }
  // c1/c2: 4-way block-parallel (one coefficient vector per block)
  if (blockIdx.x < 4) {
    int n = threadIdx.x;
    int which = blockIdx.x;
    const float* coef = (which == 0) ? gA : (which == 1) ? betaA : (which == 2) ? gB : betaB;
    float a = 0.f;
    #pragma unroll 8
    for (int k = 0; k < 256; k++) a = fmaf(coef[k], Wback[k*256 + n], a);
    float* dst = (float*)(ws + ((which == 0) ? WS_C1A : (which == 1) ? WS_C2A
                               : (which == 2) ? WS_C1B : WS_C2B));
    dst[n] = a + ((which & 1) ? bback[n] : 0.0f);
  }
  for (int i = tid; i < 2*NSPLIT*NSEG; i += stride) vz[i] = 0.0f;  // vpart+cpart
}

// 256 threads / 4 waves; wave owns cols [64w, 64w+64) of a 64-row tile.
// (256,3): 170 total regs -> 64 AGPR acc + VGPRs, zero spill (r8/r12/r13 proven).
// ZSTR=276: GEMM2 ds_read conflict-free (r9 proven, 25x reduction).
// Scatter: vpw LDS + barrier + ONE atomic pair per row (r9: per-wave direct
// atomics cost +43 us).
// r14 deltas (load scheduling, ~38 free VGPRs available):
//  (1) GEMM1 loads ALL 8 feats vectors before normalize/MFMA (was 2-in-flight
//      serial chain per mt at HBM latency);
//  (2) GEMM2 software-pipelined: kk=0 B-frags issued BEFORE the barrier
//      (w2gT independent of ztile), kk+1 prefetched under kk's MFMAs;
//  (3) bias staged to LDS with c1/c2/Wv.
// Operand-swapped MFMA: mfma(W_frag, h_frag) => lane's 4 acc regs are 4
// CONSECUTIVE cols of one row: row = 16*mt + l15, col = 64*w + 16*nt + 4*quad + r.
__global__ __launch_bounds__(256, 3) void fused_kernel(
    const float* __restrict__ featsA, const float* __restrict__ featsB,
    const float* __restrict__ bA, const float* __restrict__ bB,
    const float* __restrict__ Wv, const int* __restrict__ bidx,
    const char* __restrict__ ws, float* __restrict__ vpart, float* __restrict__ cpart,
    int tilesA, int nA, int nB)
{
  __shared__ __attribute__((aligned(16))) short ztile[64*ZSTR];
  __shared__ __attribute__((aligned(16))) float sred[64][4];
  __shared__ __attribute__((aligned(16))) float s2red[64][4];
  __shared__ __attribute__((aligned(16))) float vpw[64][4];
  __shared__ __attribute__((aligned(16))) float sc1[256], sc2[256], swv[256], sb1[256];

  const int tid  = threadIdx.x;
  const int wave = tid >> 6;
  const int lane = tid & 63;
  const int l15  = lane & 15;
  const int quad = lane >> 4;

  const bool isA = (blockIdx.x < (unsigned)tilesA);
  const int  tb  = isA ? blockIdx.x : (blockIdx.x - tilesA);
  const int  r0  = tb * 64;
  const int  nrows = isA ? nA : nB;
  const int  valid = min(64, nrows - r0);
  const int  gbase = (isA ? r0 : (nA + r0));
  const int  split = blockIdx.x & (NSPLIT - 1);
  const float* feats = isA ? featsA : featsB;
  const float* invp  = (const float*)(ws + (isA ? WS_INVA : WS_INVB));
  const float* nmip  = (const float*)(ws + (isA ? WS_NMIA : WS_NMIB));
  const float* biasp = isA ? bA : bB;
  const short* weT   = (const short*)(ws + (isA ? WS_WAT : WS_WBT2));
  const short* w2gT  = (const short*)(ws + (isA ? WS_W2GA : WS_W2GB));
  const float* c1p   = (const float*)(ws + (isA ? WS_C1A : WS_C1B));
  const float* c2p   = (const float*)(ws + (isA ? WS_C2A : WS_C2B));
  const int f       = isA ? 32 : 48;
  const int kstride = isA ? 32 : 64;
  const int ksteps  = isA ? 1 : 2;

  // ---- prefetches: scatter index + epilogue constants -> LDS (covered by barrier #1)
  int seg0 = 0;
  if (tid < valid) seg0 = bidx[gbase + tid];
  sc1[tid] = c1p[tid];
  sc2[tid] = c2p[tid];
  swv[tid] = Wv[tid];
  sb1[tid] = biasp[tid];

  // ---- GEMM1: h = relu(norm(feats) @ W1 + b1), normalize inline (fma form) ----
  floatx4 acc1[4][4];
  #pragma unroll
  for (int mt = 0; mt < 4; mt++)
    #pragma unroll
    for (int nt = 0; nt < 4; nt++)
      acc1[mt][nt] = 0.0f;

  for (int kk = 0; kk < ksteps; kk++) {
    short8 bfw[4];
    #pragma unroll
    for (int nt = 0; nt < 4; nt++) {
      unsigned boff = (unsigned)(64*wave + 16*nt + l15) * kstride + kk*32 + quad*8;
      bfw[nt] = *(const short8*)(weT + boff);
    }
    const int k0 = kk*32 + quad*8;
    const bool kvalid = (k0 < f);
    floatx4 nm0 = {0,0,0,0}, nm1 = {0,0,0,0}, iv0 = {0,0,0,0}, iv1 = {0,0,0,0};
    if (kvalid) {
      nm0 = *(const floatx4*)(nmip + k0);  nm1 = *(const floatx4*)(nmip + k0 + 4);
      iv0 = *(const floatx4*)(invp + k0);  iv1 = *(const floatx4*)(invp + k0 + 4);
    }
    // issue ALL feats loads first (8 in flight), then consume
    floatx4 xs[4][2];
    #pragma unroll
    for (int mt = 0; mt < 4; mt++) {
      int row = 16*mt + l15;
      xs[mt][0] = floatx4{0,0,0,0};
      xs[mt][1] = floatx4{0,0,0,0};
      if (kvalid && row < valid) {
        const float* fp = feats + (size_t)(r0 + row) * f + k0;
        xs[mt][0] = *(const floatx4*)fp;
        xs[mt][1] = *(const floatx4*)(fp + 4);
      }
    }
    #pragma unroll
    for (int mt = 0; mt < 4; mt++) {
      short8 a = {0,0,0,0,0,0,0,0};
      int row = 16*mt + l15;
      if (kvalid && row < valid) {
        floatx4 x0 = xs[mt][0], x1 = xs[mt][1];
        float g0 = fminf(fmaxf(fmaf(x0[0], iv0[0], nm0[0]), -5.0f), 5.0f);
        float g1 = fminf(fmaxf(fmaf(x0[1], iv0[1], nm0[1]), -5.0f), 5.0f);
        float g2 = fminf(fmaxf(fmaf(x0[2], iv0[2], nm0[2]), -5.0f), 5.0f);
        float g3 = fminf(fmaxf(fmaf(x0[3], iv0[3], nm0[3]), -5.0f), 5.0f);
        float g4 = fminf(fmaxf(fmaf(x1[0], iv1[0], nm1[0]), -5.0f), 5.0f);
        float g5 = fminf(fmaxf(fmaf(x1[1], iv1[1], nm1[1]), -5.0f), 5.0f);
        float g6 = fminf(fmaxf(fmaf(x1[2], iv1[2], nm1[2]), -5.0f), 5.0f);
        float g7 = fminf(fmaxf(fmaf(x1[3], iv1[3], nm1[3]), -5.0f), 5.0f);
        uintx4 u = { cvt2(g0, g1), cvt2(g2, g3), cvt2(g4, g5), cvt2(g6, g7) };
        a = __builtin_bit_cast(short8, u);
      }
      #pragma unroll
      for (int nt = 0; nt < 4; nt++)
        acc1[mt][nt] = __builtin_amdgcn_mfma_f32_16x16x32_bf16(bfw[nt], a, acc1[mt][nt], 0, 0, 0);
    }
  }

  // ---- epilogue1: h=relu(.+b1) -> ztile (bf16, cvt_pk packed) + per-row stats ----
  float sacc[4] = {0.f,0.f,0.f,0.f}, s2acc[4] = {0.f,0.f,0.f,0.f};
  #pragma unroll
  for (int nt = 0; nt < 4; nt++) {
    const int c0 = 64*wave + 16*nt + 4*quad;
    floatx4 b1v = *(const floatx4*)(sb1 + c0);
    #pragma unroll
    for (int mt = 0; mt < 4; mt++) {
      float h0 = fmaxf(acc1[mt][nt][0] + b1v[0], 0.0f);
      float h1 = fmaxf(acc1[mt][nt][1] + b1v[1], 0.0f);
      float h2 = fmaxf(acc1[mt][nt][2] + b1v[2], 0.0f);
      float h3 = fmaxf(acc1[mt][nt][3] + b1v[3], 0.0f);
      sacc[mt] += (h0 + h1) + (h2 + h3);
      s2acc[mt] = fmaf(h0, h0, fmaf(h1, h1, fmaf(h2, h2, fmaf(h3, h3, s2acc[mt]))));
      uintx2 pk = { cvt2(h0, h1), cvt2(h2, h3) };
      *(uintx2*)(ztile + (16*mt + l15)*ZSTR + c0) = pk;
    }
  }
  // reduce stats over the 4 quads (cols); rows are lane-local
  #pragma unroll
  for (int mt = 0; mt < 4; mt++) {
    float s = sacc[mt], s2 = s2acc[mt];
    s += __shfl_xor(s, 16, 64);  s2 += __shfl_xor(s2, 16, 64);
    s += __shfl_xor(s, 32, 64);  s2 += __shfl_xor(s2, 32, 64);
    if (lane < 16) {
      sred[16*mt + lane][wave] = s;
      s2red[16*mt + lane][wave] = s2;
    }
  }

  // ---- GEMM2 kk=0 B-frags: issue BEFORE the barrier (independent of ztile),
  // so their L2 latency overlaps the sync.
  const unsigned gbaseoff = (unsigned)(64*wave + l15)*256 + quad*8;
  short8 bfn[4];
  #pragma unroll
  for (int nt = 0; nt < 4; nt++)
    bfn[nt] = *(const short8*)(w2gT + gbaseoff + (unsigned)(16*nt)*256);
  __syncthreads();

  // ---- GEMM2: q = h @ (g*Wback), K=256, software-pipelined B loads ----
  floatx4 acc2[4][4];
  #pragma unroll
  for (int mt = 0; mt < 4; mt++)
    #pragma unroll
    for (int nt = 0; nt < 4; nt++)
      acc2[mt][nt] = 0.0f;

  #pragma unroll
  for (int kk = 0; kk < 8; kk++) {
    short8 bf[4];
    #pragma unroll
    for (int nt = 0; nt < 4; nt++) bf[nt] = bfn[nt];
    if (kk < 7) {
      #pragma unroll
      for (int nt = 0; nt < 4; nt++)
        bfn[nt] = *(const short8*)(w2gT + gbaseoff + (unsigned)(16*nt)*256 + (kk+1)*32);
    }
    #pragma unroll
    for (int mt = 0; mt < 4; mt++) {
      short8 a = *(const short8*)(ztile + (16*mt + l15)*ZSTR + kk*32 + quad*8);
      #pragma unroll
      for (int nt = 0; nt < 4; nt++)
        acc2[mt][nt] = __builtin_amdgcn_mfma_f32_16x16x32_bf16(bf[nt], a, acc2[mt][nt], 0, 0, 0);
    }
  }

  // ---- per-row LN scalars (after GEMM2, from LDS) ----
  float rsv[4], mrsv[4];
  #pragma unroll
  for (int mt = 0; mt < 4; mt++) {
    int row = 16*mt + l15;
    floatx4 sv  = *(const floatx4*)sred[row];
    floatx4 s2v = *(const floatx4*)s2red[row];
    float s  = sv[0] + sv[1] + sv[2] + sv[3];
    float s2 = s2v[0] + s2v[1] + s2v[2] + s2v[3];
    float mu  = s * (1.0f/256.0f);
    float var = fmaxf(s2 * (1.0f/256.0f) - mu*mu, 0.0f);
    float rs  = rsqrtf(var + 1e-5f);
    rsv[mt]  = rs;
    mrsv[mt] = mu * rs;
  }

  // ---- epilogue2: y = relu(rs*q - mu*rs*c1 + c2); v = y . Wv  (consts from LDS) ----
  float pv[4] = {0.f, 0.f, 0.f, 0.f};
  #pragma unroll
  for (int nt = 0; nt < 4; nt++) {
    const int c0 = 64*wave + 16*nt + 4*quad;
    floatx4 c1v = *(const floatx4*)(sc1 + c0);
    floatx4 c2v = *(const floatx4*)(sc2 + c0);
    floatx4 wvv = *(const floatx4*)(swv + c0);
    #pragma unroll
    for (int mt = 0; mt < 4; mt++) {
      float rs = rsv[mt], mrs = mrsv[mt];
      #pragma unroll
      for (int r = 0; r < 4; r++) {
        float t = fmaf(-mrs, c1v[r], c2v[r]);
        float y = fmaf(rs, acc2[mt][nt][r], t);
        y = fmaxf(y, 0.0f);
        pv[mt] = fmaf(y, wvv[r], pv[mt]);
      }
    }
  }
  #pragma unroll
  for (int mt = 0; mt < 4; mt++) {
    float p = pv[mt];
    p += __shfl_xor(p, 16, 64);
    p += __shfl_xor(p, 32, 64);
    if (lane < 16) vpw[16*mt + lane][wave] = p;
  }
  __syncthreads();

  // ---- scatter: ONE atomic pair per valid row (seg prefetched) ----
  if (tid < valid) {
    floatx4 vv = *(const floatx4*)vpw[tid];
    float v = vv[0] + vv[1] + vv[2] + vv[3];
    atomicAdd(&vpart[split*NSEG + seg0], v);
    atomicAdd(&cpart[split*NSEG + seg0], 1.0f);
  }
}

__global__ void final_kernel(const float* __restrict__ vpart, const float* __restrict__ cpart,
                             const float* __restrict__ bv, float* __restrict__ out, int nseg) {
  int s = blockIdx.x * blockDim.x + threadIdx.x;
  if (s < nseg) {
    float a = 0.0f, c = 0.0f;
    #pragma unroll 8
    for (int i = 0; i < NSPLIT; i++) { a += vpart[i*NSEG + s]; c += cpart[i*NSEG + s]; }
    out[s] = a / fmaxf(c, 1.0f) + bv[0];
  }
}

extern "C" void kernel_launch(void* const* d_in, const int* in_sizes, int n_in,
                              void* d_out, int out_size, void* d_ws, size_t ws_size,
                              hipStream_t stream) {
  const float* featsA = (const float*)d_in[0];
  const float* featsB = (const float*)d_in[1];
  const float* mA     = (const float*)d_in[2];
  const float* sA     = (const float*)d_in[3];
  const float* mB     = (const float*)d_in[4];
  const float* sB     = (const float*)d_in[5];
  const float* WA     = (const float*)d_in[6];
  const float* bA     = (const float*)d_in[7];
  const float* gA     = (const float*)d_in[8];
  const float* betaA  = (const float*)d_in[9];
  const float* WB     = (const float*)d_in[10];
  const float* bB     = (const float*)d_in[11];
  const float* gB     = (const float*)d_in[12];
  const float* betaB  = (const float*)d_in[13];
  const float* Wback  = (const float*)d_in[14];
  const float* bback  = (const float*)d_in[15];
  const float* Wv     = (const float*)d_in[16];
  const float* bv     = (const float*)d_in[17];
  const int*   bidx   = (const int*)d_in[18];

  const int nA = in_sizes[0] / 32;
  const int nB = in_sizes[1] / 48;
  char* ws = (char*)d_ws;
  float* vpart = (float*)(ws + WS_VPART);
  float* cpart = (float*)(ws + WS_CPART);
  float* out = (float*)d_out;

  prep_kernel<<<256, 256, 0, stream>>>(WA, WB, Wback, gA, betaA, gB, betaB,
                                       bback, sA, sB, mA, mB, ws);

  const int tilesA = (nA + 63) / 64;
  const int tilesB = (nB + 63) / 64;
  fused_kernel<<<tilesA + tilesB, 256, 0, stream>>>(
      featsA, featsB, bA, bB, Wv, bidx, ws, vpart, cpart, tilesA, nA, nB);

  if (out_size > 0)
    final_kernel<<<(out_size + 255) / 256, 256, 0, stream>>>(vpart, cpart, bv, out, out_size);
}

// Round 15
// 282.460 us; speedup vs baseline: 1.0513x; 1.0513x over previous
//
#include <hip/hip_runtime.h>
#include <hip/hip_bf16.h>

#define NSEG 512
#define NSPLIT 32
#define ZSTR 268   // 134 dwords = 6 mod 32 -> 6*l15 mod 32 covers 16 distinct banks (conflict-free like 276)
                   // and shrinks LDS to 40448 B/block -> 4 blocks/CU fit in 160 KiB

typedef __attribute__((ext_vector_type(8))) short short8;
typedef __attribute__((ext_vector_type(4))) float floatx4;
typedef __attribute__((ext_vector_type(4))) unsigned uintx4;
typedef __attribute__((ext_vector_type(2))) unsigned uintx2;

// ws layout (bytes), all 16B-aligned
#define WS_WAT   0        // short [256][32]   WA^T
#define WS_WBT2  16384    // short [256][64]   WB^T (K padded 48->64 w/ zeros)
#define WS_W2GA  49152    // short [256][256]  (gA*Wback)^T
#define WS_W2GB  180224   // short [256][256]  (gB*Wback)^T
#define WS_C1A   311296   // float[256] gA . Wback[:,n]
#define WS_C2A   312320   // float[256] betaA . Wback[:,n] + bback
#define WS_C1B   313344
#define WS_C2B   314368
#define WS_INVA  315392   // float[32]  1/stdA
#define WS_INVB  315520   // float[48]  1/stdB
#define WS_VPART 315712   // float [NSPLIT][NSEG]
#define WS_CPART 381248   // float [NSPLIT][NSEG]
#define WS_NMIA  446848   // float[32]  -meanA/stdA
#define WS_NMIB  446976   // float[48]  -meanB/stdB
// end 447168

__device__ __forceinline__ short f2bf(float f) {  // RNE (prep tables only)
  unsigned u = __builtin_bit_cast(unsigned, f);
  u += 0x7FFFu + ((u >> 16) & 1u);
  return (short)(u >> 16);
}

// paired RNE f32->bf16; __float22bfloat162_rn lowers to v_cvt_pk_bf16_f32.
// (__hip_bfloat162 is not trivially copyable -> memcpy, not bit_cast; r11 fix)
__device__ __forceinline__ unsigned cvt2(float lo, float hi) {
  __hip_bfloat162 b = __float22bfloat162_rn(float2{lo, hi});
  unsigned r;
  __builtin_memcpy(&r, &b, 4);
  return r;
}

// ---- prep: weight tables + c1/c2 + inv/nmi + partial-buffer zeroing.
__global__ __launch_bounds__(256) void prep_kernel(
    const float* __restrict__ WA, const float* __restrict__ WB,
    const float* __restrict__ Wback,
    const float* __restrict__ gA, const float* __restrict__ betaA,
    const float* __restrict__ gB, const float* __restrict__ betaB,
    const float* __restrict__ bback,
    const float* __restrict__ sA, const float* __restrict__ sB,
    const float* __restrict__ mA, const float* __restrict__ mB,
    char* __restrict__ ws) {
  short* waT  = (short*)(ws + WS_WAT);
  short* wbT2 = (short*)(ws + WS_WBT2);
  short* w2gA = (short*)(ws + WS_W2GA);
  short* w2gB = (short*)(ws + WS_W2GB);
  float* invA = (float*)(ws + WS_INVA);
  float* invB = (float*)(ws + WS_INVB);
  float* nmiA = (float*)(ws + WS_NMIA);
  float* nmiB = (float*)(ws + WS_NMIB);
  float* vz   = (float*)(ws + WS_VPART);
  int tid = blockIdx.x * blockDim.x + threadIdx.x;
  int stride = gridDim.x * blockDim.x;
  if (tid < 32) { float iv = 1.0f / sA[tid]; invA[tid] = iv; nmiA[tid] = -mA[tid] * iv; }
  if (tid < 48) { float iv = 1.0f / sB[tid]; invB[tid] = iv; nmiB[tid] = -mB[tid] * iv; }
  // output-indexed (coalesced writes); strided reads are L2-absorbed
  for (int i = tid; i < 32*256; i += stride) {          // waT[n][k] = WA[k][n]
    int n = i >> 5, k = i & 31;
    waT[i] = f2bf(WA[k*256 + n]);
  }
  for (int i = tid; i < 256*64; i += stride) {          // wbT2[n][k] = WB[k][n], pad K
    int n = i >> 6, k = i & 63;
    wbT2[i] = (k < 48) ? f2bf(WB[k*256 + n]) : (short)0;
  }
  for (int i = tid; i < 256*256; i += stride) {         // w2g[n][k] = g[k]*Wback[k][n]
    int n = i >> 8, k = i & 255;
    float w = Wback[k*256 + n];
    w2gA[i] = f2bf(gA[k] * w);
    w2gB[i] = f2bf(gB[k] * w);
  }
  // c1/c2: 4-way block-parallel (one coefficient vector per block)
  if (blockIdx.x < 4) {
    int n = threadIdx.x;
    int which = blockIdx.x;
    const float* coef = (which == 0) ? gA : (which == 1) ? betaA : (which == 2) ? gB : betaB;
    float a = 0.f;
    #pragma unroll 8
    for (int k = 0; k < 256; k++) a = fmaf(coef[k], Wback[k*256 + n], a);
    float* dst = (float*)(ws + ((which == 0) ? WS_C1A : (which == 1) ? WS_C2A
                               : (which == 2) ? WS_C1B : WS_C2B));
    dst[n] = a + ((which & 1) ? bback[n] : 0.0f);
  }
  for (int i = tid; i < 2*NSPLIT*NSEG; i += stride) vz[i] = 0.0f;  // vpart+cpart
}

// 256 threads / 4 waves; wave owns cols [64w, 64w+64) of a 64-row tile.
// r15 experiment: the r13 body (68 VGPR at the relaxed tier -- leanest yet)
// retried at (256,4). LDS shrunk via ZSTR 276->268 (40448 B <= 40960) so 4
// blocks/CU fit. Allocator must fit ~132 total regs into 128 -> expect a
// FEW-reg spill at most (round 3's 16-reg spill was a fat body: global
// epilogue consts, 2-op normalize, 64-bit addressing -- all since removed).
// Occupancy 30 -> ~40% if it holds. Revert trigger: WRITE>45MB or fused>185us.
// Everything else identical to r13 (best, 286.4 us): fma-normalize, cvt_pk,
// LDS-staged c1/c2/Wv, prefetched seg, one atomic pair per row.
// Operand-swapped MFMA: mfma(W_frag, h_frag) => lane's 4 acc regs are 4
// CONSECUTIVE cols of one row: row = 16*mt + l15, col = 64*w + 16*nt + 4*quad + r.
__global__ __launch_bounds__(256, 4) void fused_kernel(
    const float* __restrict__ featsA, const float* __restrict__ featsB,
    const float* __restrict__ bA, const float* __restrict__ bB,
    const float* __restrict__ Wv, const int* __restrict__ bidx,
    const char* __restrict__ ws, float* __restrict__ vpart, float* __restrict__ cpart,
    int tilesA, int nA, int nB)
{
  __shared__ __attribute__((aligned(16))) short ztile[64*ZSTR];
  __shared__ __attribute__((aligned(16))) float sred[64][4];
  __shared__ __attribute__((aligned(16))) float s2red[64][4];
  __shared__ __attribute__((aligned(16))) float vpw[64][4];
  __shared__ __attribute__((aligned(16))) float sc1[256], sc2[256], swv[256];

  const int tid  = threadIdx.x;
  const int wave = tid >> 6;
  const int lane = tid & 63;
  const int l15  = lane & 15;
  const int quad = lane >> 4;

  const bool isA = (blockIdx.x < (unsigned)tilesA);
  const int  tb  = isA ? blockIdx.x : (blockIdx.x - tilesA);
  const int  r0  = tb * 64;
  const int  nrows = isA ? nA : nB;
  const int  valid = min(64, nrows - r0);
  const int  gbase = (isA ? r0 : (nA + r0));
  const int  split = blockIdx.x & (NSPLIT - 1);
  const float* feats = isA ? featsA : featsB;
  const float* invp  = (const float*)(ws + (isA ? WS_INVA : WS_INVB));
  const float* nmip  = (const float*)(ws + (isA ? WS_NMIA : WS_NMIB));
  const float* biasp = isA ? bA : bB;
  const short* weT   = (const short*)(ws + (isA ? WS_WAT : WS_WBT2));
  const short* w2gT  = (const short*)(ws + (isA ? WS_W2GA : WS_W2GB));
  const float* c1p   = (const float*)(ws + (isA ? WS_C1A : WS_C1B));
  const float* c2p   = (const float*)(ws + (isA ? WS_C2A : WS_C2B));
  const int f       = isA ? 32 : 48;
  const int kstride = isA ? 32 : 64;
  const int ksteps  = isA ? 1 : 2;

  // ---- prefetches: scatter index + epilogue2 constants -> LDS (covered by barrier #1)
  int seg0 = 0;
  if (tid < valid) seg0 = bidx[gbase + tid];
  sc1[tid] = c1p[tid];
  sc2[tid] = c2p[tid];
  swv[tid] = Wv[tid];

  // ---- GEMM1: h = relu(norm(feats) @ W1 + b1), normalize inline (fma form) ----
  floatx4 acc1[4][4];
  #pragma unroll
  for (int mt = 0; mt < 4; mt++)
    #pragma unroll
    for (int nt = 0; nt < 4; nt++)
      acc1[mt][nt] = 0.0f;

  for (int kk = 0; kk < ksteps; kk++) {
    short8 bfw[4];
    #pragma unroll
    for (int nt = 0; nt < 4; nt++) {
      unsigned boff = (unsigned)(64*wave + 16*nt + l15) * kstride + kk*32 + quad*8;
      bfw[nt] = *(const short8*)(weT + boff);
    }
    const int k0 = kk*32 + quad*8;
    const bool kvalid = (k0 < f);
    floatx4 nm0 = {0,0,0,0}, nm1 = {0,0,0,0}, iv0 = {0,0,0,0}, iv1 = {0,0,0,0};
    if (kvalid) {
      nm0 = *(const floatx4*)(nmip + k0);  nm1 = *(const floatx4*)(nmip + k0 + 4);
      iv0 = *(const floatx4*)(invp + k0);  iv1 = *(const floatx4*)(invp + k0 + 4);
    }
    #pragma unroll
    for (int mt = 0; mt < 4; mt++) {
      short8 a = {0,0,0,0,0,0,0,0};
      int row = 16*mt + l15;
      if (kvalid && row < valid) {
        const float* fp = feats + (size_t)(r0 + row) * f + k0;
        floatx4 x0 = *(const floatx4*)fp;
        floatx4 x1 = *(const floatx4*)(fp + 4);
        float g0 = fminf(fmaxf(fmaf(x0[0], iv0[0], nm0[0]), -5.0f), 5.0f);
        float g1 = fminf(fmaxf(fmaf(x0[1], iv0[1], nm0[1]), -5.0f), 5.0f);
        float g2 = fminf(fmaxf(fmaf(x0[2], iv0[2], nm0[2]), -5.0f), 5.0f);
        float g3 = fminf(fmaxf(fmaf(x0[3], iv0[3], nm0[3]), -5.0f), 5.0f);
        float g4 = fminf(fmaxf(fmaf(x1[0], iv1[0], nm1[0]), -5.0f), 5.0f);
        float g5 = fminf(fmaxf(fmaf(x1[1], iv1[1], nm1[1]), -5.0f), 5.0f);
        float g6 = fminf(fmaxf(fmaf(x1[2], iv1[2], nm1[2]), -5.0f), 5.0f);
        float g7 = fminf(fmaxf(fmaf(x1[3], iv1[3], nm1[3]), -5.0f), 5.0f);
        uintx4 u = { cvt2(g0, g1), cvt2(g2, g3), cvt2(g4, g5), cvt2(g6, g7) };
        a = __builtin_bit_cast(short8, u);
      }
      #pragma unroll
      for (int nt = 0; nt < 4; nt++)
        acc1[mt][nt] = __builtin_amdgcn_mfma_f32_16x16x32_bf16(bfw[nt], a, acc1[mt][nt], 0, 0, 0);
    }
  }

  // ---- epilogue1: h=relu(.+b1) -> ztile (bf16, cvt_pk packed) + per-row stats ----
  float sacc[4] = {0.f,0.f,0.f,0.f}, s2acc[4] = {0.f,0.f,0.f,0.f};
  #pragma unroll
  for (int nt = 0; nt < 4; nt++) {
    const int c0 = 64*wave + 16*nt + 4*quad;
    floatx4 b1v = *(const floatx4*)(biasp + c0);
    #pragma unroll
    for (int mt = 0; mt < 4; mt++) {
      float h0 = fmaxf(acc1[mt][nt][0] + b1v[0], 0.0f);
      float h1 = fmaxf(acc1[mt][nt][1] + b1v[1], 0.0f);
      float h2 = fmaxf(acc1[mt][nt][2] + b1v[2], 0.0f);
      float h3 = fmaxf(acc1[mt][nt][3] + b1v[3], 0.0f);
      sacc[mt] += (h0 + h1) + (h2 + h3);
      s2acc[mt] = fmaf(h0, h0, fmaf(h1, h1, fmaf(h2, h2, fmaf(h3, h3, s2acc[mt]))));
      uintx2 pk = { cvt2(h0, h1), cvt2(h2, h3) };
      *(uintx2*)(ztile + (16*mt + l15)*ZSTR + c0) = pk;
    }
  }
  // reduce stats over the 4 quads (cols); rows are lane-local
  #pragma unroll
  for (int mt = 0; mt < 4; mt++) {
    float s = sacc[mt], s2 = s2acc[mt];
    s += __shfl_xor(s, 16, 64);  s2 += __shfl_xor(s2, 16, 64);
    s += __shfl_xor(s, 32, 64);  s2 += __shfl_xor(s2, 32, 64);
    if (lane < 16) {
      sred[16*mt + lane][wave] = s;
      s2red[16*mt + lane][wave] = s2;
    }
  }
  __syncthreads();

  // ---- GEMM2: q = h @ (g*Wback), K=256 ----
  floatx4 acc2[4][4];
  #pragma unroll
  for (int mt = 0; mt < 4; mt++)
    #pragma unroll
    for (int nt = 0; nt < 4; nt++)
      acc2[mt][nt] = 0.0f;

  #pragma unroll 2
  for (int kk = 0; kk < 8; kk++) {
    short8 bf[4];
    #pragma unroll
    for (int nt = 0; nt < 4; nt++) {
      unsigned goff = (unsigned)(64*wave + 16*nt + l15)*256 + kk*32 + quad*8;
      bf[nt] = *(const short8*)(w2gT + goff);
    }
    #pragma unroll
    for (int mt = 0; mt < 4; mt++) {
      short8 a = *(const short8*)(ztile + (16*mt + l15)*ZSTR + kk*32 + quad*8);
      #pragma unroll
      for (int nt = 0; nt < 4; nt++)
        acc2[mt][nt] = __builtin_amdgcn_mfma_f32_16x16x32_bf16(bf[nt], a, acc2[mt][nt], 0, 0, 0);
    }
  }

  // ---- per-row LN scalars (after GEMM2, from LDS) ----
  float rsv[4], mrsv[4];
  #pragma unroll
  for (int mt = 0; mt < 4; mt++) {
    int row = 16*mt + l15;
    floatx4 sv  = *(const floatx4*)sred[row];
    floatx4 s2v = *(const floatx4*)s2red[row];
    float s  = sv[0] + sv[1] + sv[2] + sv[3];
    float s2 = s2v[0] + s2v[1] + s2v[2] + s2v[3];
    float mu  = s * (1.0f/256.0f);
    float var = fmaxf(s2 * (1.0f/256.0f) - mu*mu, 0.0f);
    float rs  = rsqrtf(var + 1e-5f);
    rsv[mt]  = rs;
    mrsv[mt] = mu * rs;
  }

  // ---- epilogue2: y = relu(rs*q - mu*rs*c1 + c2); v = y . Wv  (consts from LDS) ----
  float pv[4] = {0.f, 0.f, 0.f, 0.f};
  #pragma unroll
  for (int nt = 0; nt < 4; nt++) {
    const int c0 = 64*wave + 16*nt + 4*quad;
    floatx4 c1v = *(const floatx4*)(sc1 + c0);
    floatx4 c2v = *(const floatx4*)(sc2 + c0);
    floatx4 wvv = *(const floatx4*)(swv + c0);
    #pragma unroll
    for (int mt = 0; mt < 4; mt++) {
      float rs = rsv[mt], mrs = mrsv[mt];
      #pragma unroll
      for (int r = 0; r < 4; r++) {
        float t = fmaf(-mrs, c1v[r], c2v[r]);
        float y = fmaf(rs, acc2[mt][nt][r], t);
        y = fmaxf(y, 0.0f);
        pv[mt] = fmaf(y, wvv[r], pv[mt]);
      }
    }
  }
  #pragma unroll
  for (int mt = 0; mt < 4; mt++) {
    float p = pv[mt];
    p += __shfl_xor(p, 16, 64);
    p += __shfl_xor(p, 32, 64);
    if (lane < 16) vpw[16*mt + lane][wave] = p;
  }
  __syncthreads();

  // ---- scatter: ONE atomic pair per valid row (seg prefetched) ----
  if (tid < valid) {
    floatx4 vv = *(const floatx4*)vpw[tid];
    float v = vv[0] + vv[1] + vv[2] + vv[3];
    atomicAdd(&vpart[split*NSEG + seg0], v);
    atomicAdd(&cpart[split*NSEG + seg0], 1.0f);
  }
}

__global__ void final_kernel(const float* __restrict__ vpart, const float* __restrict__ cpart,
                             const float* __restrict__ bv, float* __restrict__ out, int nseg) {
  int s = blockIdx.x * blockDim.x + threadIdx.x;
  if (s < nseg) {
    float a = 0.0f, c = 0.0f;
    #pragma unroll 8
    for (int i = 0; i < NSPLIT; i++) { a += vpart[i*NSEG + s]; c += cpart[i*NSEG + s]; }
    out[s] = a / fmaxf(c, 1.0f) + bv[0];
  }
}

extern "C" void kernel_launch(void* const* d_in, const int* in_sizes, int n_in,
                              void* d_out, int out_size, void* d_ws, size_t ws_size,
                              hipStream_t stream) {
  const float* featsA = (const float*)d_in[0];
  const float* featsB = (const float*)d_in[1];
  const float* mA     = (const float*)d_in[2];
  const float* sA     = (const float*)d_in[3];
  const float* mB     = (const float*)d_in[4];
  const float* sB     = (const float*)d_in[5];
  const float* WA     = (const float*)d_in[6];
  const float* bA     = (const float*)d_in[7];
  const float* gA     = (const float*)d_in[8];
  const float* betaA  = (const float*)d_in[9];
  const float* WB     = (const float*)d_in[10];
  const float* bB     = (const float*)d_in[11];
  const float* gB     = (const float*)d_in[12];
  const float* betaB  = (const float*)d_in[13];
  const float* Wback  = (const float*)d_in[14];
  const float* bback  = (const float*)d_in[15];
  const float* Wv     = (const float*)d_in[16];
  const float* bv     = (const float*)d_in[17];
  const int*   bidx   = (const int*)d_in[18];

  const int nA = in_sizes[0] / 32;
  const int nB = in_sizes[1] / 48;
  char* ws = (char*)d_ws;
  float* vpart = (float*)(ws + WS_VPART);
  float* cpart = (float*)(ws + WS_CPART);
  float* out = (float*)d_out;

  prep_kernel<<<256, 256, 0, stream>>>(WA, WB, Wback, gA, betaA, gB, betaB,
                                       bback, sA, sB, mA, mB, ws);

  const int tilesA = (nA + 63) / 64;
  const int tilesB = (nB + 63) / 64;
  fused_kernel<<<tilesA + tilesB, 256, 0, stream>>>(
      featsA, featsB, bA, bB, Wv, bidx, ws, vpart, cpart, tilesA, nA, nB);

  if (out_size > 0)
    final_kernel<<<(out_size + 255) / 256, 256, 0, stream>>>(vpart, cpart, bv, out, out_size);
}